// Round 17
// baseline (297.022 us; speedup 1.0000x reference)
//
#include <hip/hip_runtime.h>

// MultiHeadAttention B=2,S=2048,E=512,H=8,dh=64 — bf16 MFMA, split-K flash.
// Head mapping (VERIFIED r3): flat reinterpretation — head h of batch b is the
// contiguous [2048][64] span at flat offset (b*8+h)*S*64 of [4096][512].
// h is ROW-determined (r10); V transpose must use the flat view (vtrans).
// R17 = r16 (177us, flag-gated mask skip) + r14's Ps-deletion (in-register
// ds_bpermute P transform — CORRECTNESS-verified in r14) at 6 blocks/CU
// (launch_bounds(256,6), not 8: instantaneous K/V working set 3MB < 4MB L2;
// r14's regression was the now-deleted mask stream thrashing L2 at high
// occupancy). attn LDS 36.9 -> 18.4 KB. LOCKED RULES: mask loads at use point
// only (r6/r12). Fixed-m softmax (r13), scale folded into Q, Opart fp16.

#define SEQ 2048
#define EMB 512
#define DH  64
#define MROWS 4096
#define NROWS 32768   // 16 heads * 2048 rows

typedef float  v4f __attribute__((ext_vector_type(4)));
typedef short  v8s __attribute__((ext_vector_type(8)));
typedef __fp16 v2h __attribute__((ext_vector_type(2)));

static __device__ __forceinline__ unsigned int f2bf(float f) {
    unsigned int u = __float_as_uint(f);
    u += 0x7fffu + ((u >> 16) & 1u);       // RNE
    return u >> 16;
}
static __device__ __forceinline__ unsigned int pack2(float a, float b) {
    return f2bf(a) | (f2bf(b) << 16);
}
static __device__ __forceinline__ unsigned int packh2(float a, float b) {
    v2h h = __builtin_amdgcn_cvt_pkrtz(a, b);
    return __builtin_bit_cast(unsigned int, h);
}

// ---------------------------------------------------------------------------
// Mega kernel: blocks 0..767 = projection (64m x 128n, BK=64, XCD swizzle,
// dense staging — r9-verified; z==0 folds `scale`); blocks 768..1279 =
// mask pre-tile to fp32 C-layout tiles + nonzero flag (skip store if zero).
// ---------------------------------------------------------------------------
__global__ __launch_bounds__(256, 3) void proj_kernel(
    const float* __restrict__ q, const float* __restrict__ k, const float* __restrict__ v,
    const float* __restrict__ Wq, const float* __restrict__ bq,
    const float* __restrict__ Wk, const float* __restrict__ bk,
    const float* __restrict__ Wv, const float* __restrict__ bv,
    const float* __restrict__ mask,
    unsigned short* __restrict__ Qbf, unsigned short* __restrict__ Kbf,
    unsigned short* __restrict__ Vbf, float* __restrict__ maskT,
    unsigned int* __restrict__ flags)
{
    __shared__ __align__(16) char smem[27648];   // As 64x144 | Ws 128x144
    const int tid = threadIdx.x;

    // ---- mask pre-tile blocks (independent of projection) ----
    if (blockIdx.x >= 768) {
        const int mb2 = blockIdx.x - 768;
        const int rb = mb2 >> 5, kt = mb2 & 31;
        float* tile = maskT + ((size_t)rb * 32 + kt) * 8192;   // 2048 slots x 4 fp32
        float4 vals[8];
        bool any = false;
#pragma unroll
        for (int i = 0; i < 8; ++i) {
            int s = tid + i * 256;             // 0..2047
            int l  = s & 63;
            int cb = (s >> 6) & 3;
            int g  = (s >> 8) & 1;
            int w2 = (s >> 9) & 3;
            int qd2 = l >> 4, n2 = l & 15;
            vals[i] = *(const float4*)&mask[
                (size_t)(rb * 128 + w2 * 32 + g * 16 + n2) * SEQ + kt * 64 + cb * 16 + qd2 * 4];
            any = any | (vals[i].x != 0.f) | (vals[i].y != 0.f)
                      | (vals[i].z != 0.f) | (vals[i].w != 0.f);
        }
        unsigned int* nzp = (unsigned int*)smem;
        if (tid == 0) *nzp = 0u;
        __syncthreads();
        if (any) *nzp = 1u;                    // benign race (all write 1)
        __syncthreads();
        if (*nzp) {
#pragma unroll
            for (int i = 0; i < 8; ++i) {
                int s = tid + i * 256;
                *(float4*)&tile[(size_t)s * 4] = vals[i];
            }
            if (tid == 0) atomicOr(&flags[rb], 1u << kt);
        }
        return;
    }

    char* As = smem;
    char* Ws = smem + 9216;

    const int id  = blockIdx.x;
    const int pos = id & 31;
    const int nb  = pos >> 3;
    const int unit = (id >> 5) * 8 + (pos & 7);
    const int mb = unit & 63;
    const int z  = unit >> 6;

    const float* A    = (z == 0) ? q  : (z == 1) ? k  : v;
    const float* W    = (z == 0) ? Wq : (z == 1) ? Wk : Wv;
    const float* bias = (z == 0) ? bq : (z == 1) ? bk : bv;
    unsigned short* Cg = (z == 0) ? Qbf : (z == 1) ? Kbf : Vbf;

    const int w    = tid >> 6;
    const int lane = tid & 63;
    const int qd   = lane >> 4;
    const int n    = lane & 15;
    const int m0 = mb * 64, n0 = nb * 128;

    float4 areg[4], wreg[8];
#pragma unroll
    for (int i = 0; i < 4; ++i) {
        int c = tid + i * 256;                 // A: 1024 chunks, row=c>>4
        areg[i] = *(const float4*)&A[(size_t)(m0 + (c >> 4)) * EMB + (c & 15) * 4];
    }
#pragma unroll
    for (int i = 0; i < 8; ++i) {
        int c = tid + i * 256;                 // W: 2048 chunks, row=c>>4
        wreg[i] = *(const float4*)&W[(size_t)(n0 + (c >> 4)) * EMB + (c & 15) * 4];
    }

    v4f acc[8];
#pragma unroll
    for (int cb = 0; cb < 8; ++cb) acc[cb] = (v4f)0.f;

#pragma unroll 1
    for (int kt = 0; kt < 8; ++kt) {
        __syncthreads();
#pragma unroll
        for (int i = 0; i < 4; ++i) {
            int c = tid + i * 256;
            uint2 pk = { pack2(areg[i].x, areg[i].y), pack2(areg[i].z, areg[i].w) };
            *(uint2*)&As[(c >> 4) * 144 + (c & 15) * 8] = pk;
        }
#pragma unroll
        for (int i = 0; i < 8; ++i) {
            int c = tid + i * 256;
            uint2 pk = { pack2(wreg[i].x, wreg[i].y), pack2(wreg[i].z, wreg[i].w) };
            *(uint2*)&Ws[(c >> 4) * 144 + (c & 15) * 8] = pk;
        }
        __syncthreads();

        if (kt + 1 < 8) {
#pragma unroll
            for (int i = 0; i < 4; ++i) {
                int c = tid + i * 256;
                areg[i] = *(const float4*)&A[(size_t)(m0 + (c >> 4)) * EMB + (kt+1) * 64 + (c & 15) * 4];
            }
#pragma unroll
            for (int i = 0; i < 8; ++i) {
                int c = tid + i * 256;
                wreg[i] = *(const float4*)&W[(size_t)(n0 + (c >> 4)) * EMB + (kt+1) * 64 + (c & 15) * 4];
            }
        }

#pragma unroll
        for (int ks = 0; ks < 2; ++ks) {
            v8s af = *(const v8s*)&As[(w * 16 + n) * 144 + ks * 64 + qd * 16];
#pragma unroll
            for (int cb = 0; cb < 8; ++cb) {
                v8s bfr = *(const v8s*)&Ws[(cb * 16 + n) * 144 + ks * 64 + qd * 16];
                acc[cb] = __builtin_amdgcn_mfma_f32_16x16x32_bf16(af, bfr, acc[cb], 0, 0, 0);
            }
        }
    }

    const float osc = (z == 0) ? 0.02209708691207961f : 1.0f;  // fold scale into Q
    float bb[8];
#pragma unroll
    for (int cb = 0; cb < 8; ++cb) bb[cb] = bias[n0 + cb * 16 + n];
#pragma unroll
    for (int cb = 0; cb < 8; ++cb)
#pragma unroll
        for (int r = 0; r < 4; ++r) acc[cb][r] = (acc[cb][r] + bb[cb]) * osc;

    __syncthreads();
    short* Ct = (short*)smem;                  // Ct[64 rows][136 pitch]
#pragma unroll
    for (int cb = 0; cb < 8; ++cb)
#pragma unroll
        for (int r = 0; r < 4; ++r)
            Ct[(w * 16 + qd * 4 + r) * 136 + cb * 16 + n] = (short)f2bf(acc[cb][r]);
    __syncthreads();
    const int rr = tid >> 2, q4 = tid & 3;
#pragma unroll
    for (int i = 0; i < 4; ++i) {
        uint4 t4 = *(const uint4*)&smem[rr * 272 + q4 * 64 + i * 16];
        *(uint4*)&Cg[(size_t)(m0 + rr) * EMB + n0 + q4 * 32 + i * 8] = t4;
    }
}

// ---------------------------------------------------------------------------
// V tile-transpose (r9-VERIFIED; reads the flat head view): Vbf head block
// [2048][64] -> VtT[bh][kt][d][64] bf16 (contiguous 8 KB tiles). Grid (16,32).
// ---------------------------------------------------------------------------
__global__ __launch_bounds__(256) void vtrans_kernel(
    const unsigned short* __restrict__ Vbf, unsigned short* __restrict__ VtT)
{
    __shared__ unsigned short T[64 * 136];
    const int bh = blockIdx.x, kt = blockIdx.y;
    const int tid = threadIdx.x;
    const unsigned short* Vh = Vbf + (size_t)bh * (SEQ * DH) + (size_t)kt * 64 * DH;
#pragma unroll
    for (int i = 0; i < 2; ++i) {
        int c = tid + i * 256;                 // 512 uint4 chunks, dense
        int s_l = c >> 3, ch = c & 7;
        uint4 t4 = *(const uint4*)&Vh[c * 8];
        const unsigned short* e = (const unsigned short*)&t4;
#pragma unroll
        for (int j = 0; j < 8; ++j)
            T[(ch * 8 + j) * 136 + s_l] = e[j];
    }
    __syncthreads();
    unsigned short* Ot = VtT + ((size_t)bh * 32 + kt) * (64 * 64);
    const int d = tid >> 2, sq = tid & 3;
#pragma unroll
    for (int i = 0; i < 2; ++i) {
        uint4 t4 = *(const uint4*)&T[d * 136 + sq * 16 + i * 8];
        *(uint4*)&Ot[d * 64 + sq * 16 + i * 8] = t4;
    }
}

// ---------------------------------------------------------------------------
// Flash attention, bf16 MFMA, transposed scores, split-K, XCD swizzle (r7).
// Mask tile = C operand of scores MFMA, flag-gated, AT USE POINT. P transform
// C-layout -> B-fragment in registers via ds_bpermute (r14-verified): lane
// (qd,n) takes 2 dwords from lane ((2qd)&3)*16+n and 2 from ((2qd+1)&3)*16+n.
// LDS = Ks+Vts = 18432 B; 6 blocks/CU (L2 working-set safe).
// ---------------------------------------------------------------------------
template <int SPLITS>
__global__ __launch_bounds__(256, 6) void attn_kernel(
    const unsigned short* __restrict__ Qbf, const unsigned short* __restrict__ Kbf,
    const unsigned short* __restrict__ VtT,
    const float* __restrict__ maskT, const float* __restrict__ maskf,
    const unsigned int* __restrict__ flags,
    unsigned short* __restrict__ Opart, float* __restrict__ ml,
    float* __restrict__ out)
{
    __shared__ __align__(16) char smem[18432];  // Ks 64x144 | Vts 64x144
    char* Ks  = smem;
    char* Vts = smem + 9216;

    const int tid  = threadIdx.x;
    const int w    = tid >> 6;
    const int lane = tid & 63;
    const int qd   = lane >> 4;
    const int n    = lane & 15;

    const int id = blockIdx.x;
    const int rb = ((id >> 3) & 1) * 8 + (id & 7);
    const int bh = (id >> 4) & 15;
    const int kq = id >> 8;
    const int KT0 = kq * (32 / SPLITS), KT1 = KT0 + 32 / SPLITS;

    const unsigned short* Qh = Qbf + (size_t)bh * (SEQ * DH);
    const unsigned short* Kh = Kbf + (size_t)bh * (SEQ * DH);
    const unsigned short* Vth = VtT + (size_t)bh * 32 * 4096;

    const unsigned int fl = (SPLITS > 1) ? flags[rb] : 0u;   // block-uniform

    // bpermute source-lane addresses (byte addr = lane*4)
    const int aL1 = ((((2 * qd) & 3) * 16) + n) * 4;
    const int aL2 = ((((2 * qd + 1) & 3) * 16) + n) * 4;
    const bool hi = (qd >= 2);

    v8s qf[2][2];
#pragma unroll
    for (int g = 0; g < 2; ++g) {
        const size_t qrow = (size_t)(rb * 128 + w * 32 + g * 16 + n);
#pragma unroll
        for (int ks = 0; ks < 2; ++ks)
            qf[g][ks] = *(const v8s*)&Qh[qrow * DH + ks * 32 + qd * 8];
    }

    // dense staging: thread covers 16B chunks c=tid, c=tid+256 of the 8 KB tile
    uint4 kreg[2], vreg[2];
#pragma unroll
    for (int p = 0; p < 2; ++p) {
        int c = tid + p * 256;
        kreg[p] = *(const uint4*)&Kh[(size_t)KT0 * 4096 + c * 8];
        vreg[p] = *(const uint4*)&Vth[(size_t)KT0 * 4096 + c * 8];
    }

    float l_[2] = { 0.f, 0.f };
    v4f oacc[2][4];
#pragma unroll
    for (int g = 0; g < 2; ++g)
#pragma unroll
        for (int cb = 0; cb < 4; ++cb) oacc[g][cb] = (v4f)0.f;

#pragma unroll 1
    for (int kt = KT0; kt < KT1; ++kt) {
        __syncthreads();
#pragma unroll
        for (int p = 0; p < 2; ++p) {
            int c = tid + p * 256;
            *(uint4*)&Ks [(c >> 3) * 144 + (c & 7) * 16] = kreg[p];
            *(uint4*)&Vts[(c >> 3) * 144 + (c & 7) * 16] = vreg[p];
        }
        __syncthreads();

        // ---- mask tile: only load if nonzero (flag bit); AT USE POINT
        v4f sacc[2][4];
        float4 mk[2][4];
        if (SPLITS > 1) {
            if (fl & (1u << kt)) {
                const float* tileF = maskT + ((size_t)rb * 32 + kt) * 8192;
#pragma unroll
                for (int g = 0; g < 2; ++g)
#pragma unroll
                    for (int cb = 0; cb < 4; ++cb)
                        sacc[g][cb] = *(const v4f*)&tileF[
                            (size_t)((((w * 2 + g) * 4 + cb) * 64) + qd * 16 + n) * 4];
            } else {
#pragma unroll
                for (int g = 0; g < 2; ++g)
#pragma unroll
                    for (int cb = 0; cb < 4; ++cb) sacc[g][cb] = (v4f)0.f;
            }
        } else {
#pragma unroll
            for (int g = 0; g < 2; ++g) {
                const size_t mrow = (size_t)(rb * 128 + w * 32 + g * 16 + n);
#pragma unroll
                for (int cb = 0; cb < 4; ++cb) {
                    mk[g][cb] = *(const float4*)&maskf[mrow * SEQ + kt * 64 + cb * 16 + qd * 4];
                    sacc[g][cb] = (v4f)0.f;
                }
            }
        }

        if (kt + 1 < KT1) {
#pragma unroll
            for (int p = 0; p < 2; ++p) {
                int c = tid + p * 256;
                kreg[p] = *(const uint4*)&Kh[(size_t)(kt + 1) * 4096 + c * 8];
                vreg[p] = *(const uint4*)&Vth[(size_t)(kt + 1) * 4096 + c * 8];
            }
        }

        // ---- scores: S^T[s_k][qrow], accumulated onto the mask tile
#pragma unroll
        for (int ks = 0; ks < 2; ++ks)
#pragma unroll
            for (int cb = 0; cb < 4; ++cb) {
                v8s kf = *(const v8s*)&Ks[(cb * 16 + n) * 144 + ks * 64 + qd * 16];
#pragma unroll
                for (int g = 0; g < 2; ++g)
                    sacc[g][cb] = __builtin_amdgcn_mfma_f32_16x16x32_bf16(kf, qf[g][ks], sacc[g][cb], 0, 0, 0);
            }

        // ---- fixed-m softmax + in-register P transform (r14-verified)
        v8s pf[2][2];
#pragma unroll
        for (int g = 0; g < 2; ++g) {
            float rs = 0.f;
            float pv[4][4];
#pragma unroll
            for (int cb = 0; cb < 4; ++cb) {
                if (SPLITS == 1) {
                    sacc[g][cb][0] += mk[g][cb].x; sacc[g][cb][1] += mk[g][cb].y;
                    sacc[g][cb][2] += mk[g][cb].z; sacc[g][cb][3] += mk[g][cb].w;
                }
#pragma unroll
                for (int r = 0; r < 4; ++r) {
                    float e = __expf(sacc[g][cb][r]);
                    pv[cb][r] = e;
                    rs += e;
                }
            }
            rs += __shfl_xor(rs, 16);
            rs += __shfl_xor(rs, 32);
            l_[g] += rs;

            uint2 pk[4];
#pragma unroll
            for (int cb = 0; cb < 4; ++cb)
                pk[cb] = (uint2){ pack2(pv[cb][0], pv[cb][1]), pack2(pv[cb][2], pv[cb][3]) };

#pragma unroll
            for (int ks = 0; ks < 2; ++ks) {
                const int c0 = ks * 2, c1 = ks * 2 + 1;
                int a0 = __builtin_amdgcn_ds_bpermute(aL1, (int)pk[c0].x);
                int b0 = __builtin_amdgcn_ds_bpermute(aL1, (int)pk[c1].x);
                int a1 = __builtin_amdgcn_ds_bpermute(aL1, (int)pk[c0].y);
                int b1 = __builtin_amdgcn_ds_bpermute(aL1, (int)pk[c1].y);
                int a2 = __builtin_amdgcn_ds_bpermute(aL2, (int)pk[c0].x);
                int b2 = __builtin_amdgcn_ds_bpermute(aL2, (int)pk[c1].x);
                int a3 = __builtin_amdgcn_ds_bpermute(aL2, (int)pk[c0].y);
                int b3 = __builtin_amdgcn_ds_bpermute(aL2, (int)pk[c1].y);
                uint4 u = { (unsigned)(hi ? b0 : a0), (unsigned)(hi ? b1 : a1),
                            (unsigned)(hi ? b2 : a2), (unsigned)(hi ? b3 : a3) };
                pf[g][ks] = __builtin_bit_cast(v8s, u);
            }
        }

        // ---- PV: O^T[d][qrow] += Vt * P^T
#pragma unroll
        for (int ks = 0; ks < 2; ++ks)
#pragma unroll
            for (int cb = 0; cb < 4; ++cb) {
                v8s vf = *(const v8s*)&Vts[(cb * 16 + n) * 144 + ks * 64 + qd * 16];
#pragma unroll
                for (int g = 0; g < 2; ++g)
                    oacc[g][cb] = __builtin_amdgcn_mfma_f32_16x16x32_bf16(vf, pf[g][ks], oacc[g][cb], 0, 0, 0);
            }
    }

    // ---- epilogue
    if (SPLITS == 1) {
#pragma unroll
        for (int g = 0; g < 2; ++g) {
            const float inv = 1.0f / l_[g];
#pragma unroll
            for (int cb = 0; cb < 4; ++cb)
#pragma unroll
                for (int r = 0; r < 4; ++r) oacc[g][cb][r] *= inv;
        }
    } else {
        if (qd == 0) {   // lanes 0..15 hold l for rows g*16+n (dup across qd)
#pragma unroll
            for (int g = 0; g < 2; ++g) {
                const size_t row = (size_t)bh * SEQ + rb * 128 + w * 32 + g * 16 + n;
                ml[(size_t)kq * NROWS + row] = l_[g];
            }
        }
    }

    // 2-pass transpose (64 rows x 272 B = 17408 <= 18432) — r14-verified
#pragma unroll 1
    for (int g = 0; g < 2; ++g) {
        __syncthreads();
#pragma unroll
        for (int cb = 0; cb < 4; ++cb)
            *(v4f*)&smem[(w * 16 + n) * 272 + cb * 64 + qd * 16] = oacc[g][cb];
        __syncthreads();
        const int r_l = tid >> 2, qq = tid & 3;
        const int grow = rb * 128 + (r_l >> 4) * 32 + g * 16 + (r_l & 15);
        if (SPLITS == 1) {
            float* dst = &out[((size_t)bh * SEQ + grow) * DH + qq * 16];
#pragma unroll
            for (int i = 0; i < 4; ++i)
                *(float4*)&dst[i * 4] = *(const float4*)&smem[r_l * 272 + qq * 64 + i * 16];
        } else {
            unsigned short* dst = &Opart[((size_t)kq * NROWS + (size_t)bh * SEQ + grow) * DH + qq * 16];
#pragma unroll
            for (int i = 0; i < 2; ++i) {
                float4 f0 = *(const float4*)&smem[r_l * 272 + qq * 64 + i * 32];
                float4 f1 = *(const float4*)&smem[r_l * 272 + qq * 64 + i * 32 + 16];
                uint4 o = { packh2(f0.x, f0.y), packh2(f0.z, f0.w),
                            packh2(f1.x, f1.y), packh2(f1.z, f1.w) };
                *(uint4*)&dst[i * 8] = o;
            }
        }
    }
}

// ---------------------------------------------------------------------------
// Combine split-K partials (Opart fp16): out = sum_s O_s / sum_s l_s.
// ---------------------------------------------------------------------------
__global__ __launch_bounds__(256) void combine_kernel(
    const unsigned int* __restrict__ Opart, const float* __restrict__ ml,
    float* __restrict__ out, int splits)
{
    const int tid = threadIdx.x;
    const size_t row = (size_t)blockIdx.x * 16 + (tid >> 4);
    const int d4 = (tid & 15) * 4;
    float denom = 0.f;
    float4 o = make_float4(0.f, 0.f, 0.f, 0.f);
    for (int s = 0; s < splits; ++s) {
        denom += ml[(size_t)s * NROWS + row];
        uint2 u = *(const uint2*)&Opart[((size_t)s * NROWS + row) * 32 + (d4 >> 1)];
        v2h h0 = __builtin_bit_cast(v2h, u.x);
        v2h h1 = __builtin_bit_cast(v2h, u.y);
        o.x += (float)h0.x; o.y += (float)h0.y;
        o.z += (float)h1.x; o.w += (float)h1.y;
    }
    const float inv = 1.0f / denom;
    o.x *= inv; o.y *= inv; o.z *= inv; o.w *= inv;
    *(float4*)&out[row * DH + d4] = o;
}

extern "C" void kernel_launch(void* const* d_in, const int* in_sizes, int n_in,
                              void* d_out, int out_size, void* d_ws, size_t ws_size,
                              hipStream_t stream) {
    const float* q    = (const float*)d_in[0];
    const float* k    = (const float*)d_in[1];
    const float* v    = (const float*)d_in[2];
    const float* mask = (const float*)d_in[3];
    const float* Wq   = (const float*)d_in[4];
    const float* bq   = (const float*)d_in[5];
    const float* Wk   = (const float*)d_in[6];
    const float* bk   = (const float*)d_in[7];
    const float* Wv   = (const float*)d_in[8];
    const float* bv   = (const float*)d_in[9];

    char* ws = (char*)d_ws;
    const size_t MB = 1024 * 1024;
    unsigned short* Qbf   = (unsigned short*)(ws + 0);         //  0..4  MB
    unsigned short* Kbf   = (unsigned short*)(ws + 4 * MB);    //  4..8  MB
    unsigned short* VtT   = (unsigned short*)(ws + 8 * MB);    //  8..12 MB
    unsigned short* Opart = (unsigned short*)(ws + 12 * MB);   // 12..28 MB (fp16)
    unsigned short* Vbf   = (unsigned short*)(ws + 12 * MB);   // overlay, dead after vtrans
    float*          mlp   = (float*)(ws + 28 * MB);            // 28..28.5 MB (512 KB used)
    unsigned int*   flags = (unsigned int*)(ws + 28 * MB + 512 * 1024);  // 64 B
    float*          maskT = (float*)(ws + 29 * MB);            // 29..45 MB (fp32)

    const size_t need_split = 45 * MB;                         // ws >= 49 MB proven (r4)
    const bool do_split = ws_size >= need_split;

    if (do_split) {
        (void)hipMemsetAsync(flags, 0, 64, stream);            // zero the 16-word bitmap
        proj_kernel<<<1280, 256, 0, stream>>>(q, k, v, Wq, bq, Wk, bk, Wv, bv,
                                              mask, Qbf, Kbf, Vbf, maskT, flags);
        dim3 tgrid(16, 32);
        vtrans_kernel<<<tgrid, 256, 0, stream>>>(Vbf, VtT);
        attn_kernel<4><<<1024, 256, 0, stream>>>(Qbf, Kbf, VtT, maskT, mask, flags,
                                                 Opart, mlp, (float*)d_out);
        combine_kernel<<<NROWS / 16, 256, 0, stream>>>((const unsigned int*)Opart,
                                                       mlp, (float*)d_out, 4);
    } else {
        proj_kernel<<<768, 256, 0, stream>>>(q, k, v, Wq, bq, Wk, bk, Wv, bv,
                                             mask, Qbf, Kbf, Vbf, maskT, flags);
        dim3 tgrid(16, 32);
        vtrans_kernel<<<tgrid, 256, 0, stream>>>(Vbf, VtT);
        attn_kernel<1><<<256, 256, 0, stream>>>(Qbf, Kbf, VtT, maskT, mask, flags,
                                                Opart, mlp, (float*)d_out);
    }
}

// Round 18
// 174.876 us; speedup vs baseline: 1.6985x; 1.6985x over previous
//
#include <hip/hip_runtime.h>

// MultiHeadAttention B=2,S=2048,E=512,H=8,dh=64 — bf16 MFMA, split-K flash.
// FINAL (r18 = exact r16, session best 177.3us).
// Head mapping (VERIFIED r3): flat reinterpretation — head h of batch b is the
// contiguous [2048][64] span at flat offset (b*8+h)*S*64 of [4096][512].
// h is ROW-determined (r10); V transpose must use the flat view (vtrans).
// Structure: proj mega-kernel (64x128 MFMA tiles, dense staging, XCD swizzle,
// scale folded into Q; + mask pre-tile blocks w/ nonzero bitmap) -> vtrans ->
// split-K x4 flash attention (transposed scores, mask fp32 C-layout tile as
// scores-MFMA C operand, flag-gated; fixed-m softmax; dense K/V staging;
// Opart fp16) -> combine.
// EMPIRICAL LAWS (thrice-confirmed): (1) mask loads at USE POINT only —
// prefetch collapses L2 hit rate (r6: 114->244MB, r12: 54->240MB);
// (2) attn occupancy capped at 4 blocks/CU — 6-8 blocks/CU desyncs the
// co-resident set and thrashes L2 regardless of mask (r14: 269MB, r17: 273MB).

#define SEQ 2048
#define EMB 512
#define DH  64
#define MROWS 4096
#define NROWS 32768   // 16 heads * 2048 rows

typedef float  v4f __attribute__((ext_vector_type(4)));
typedef short  v8s __attribute__((ext_vector_type(8)));
typedef __fp16 v2h __attribute__((ext_vector_type(2)));

static __device__ __forceinline__ unsigned int f2bf(float f) {
    unsigned int u = __float_as_uint(f);
    u += 0x7fffu + ((u >> 16) & 1u);       // RNE
    return u >> 16;
}
static __device__ __forceinline__ unsigned int pack2(float a, float b) {
    return f2bf(a) | (f2bf(b) << 16);
}
static __device__ __forceinline__ unsigned int packh2(float a, float b) {
    v2h h = __builtin_amdgcn_cvt_pkrtz(a, b);
    return __builtin_bit_cast(unsigned int, h);
}

// ---------------------------------------------------------------------------
// Mega kernel: blocks 0..767 = projection (64m x 128n, BK=64, XCD swizzle,
// dense staging — r9-verified; z==0 folds `scale`); blocks 768..1279 =
// mask pre-tile to fp32 C-layout tiles + nonzero flag (skip store if zero).
// ---------------------------------------------------------------------------
__global__ __launch_bounds__(256, 3) void proj_kernel(
    const float* __restrict__ q, const float* __restrict__ k, const float* __restrict__ v,
    const float* __restrict__ Wq, const float* __restrict__ bq,
    const float* __restrict__ Wk, const float* __restrict__ bk,
    const float* __restrict__ Wv, const float* __restrict__ bv,
    const float* __restrict__ mask,
    unsigned short* __restrict__ Qbf, unsigned short* __restrict__ Kbf,
    unsigned short* __restrict__ Vbf, float* __restrict__ maskT,
    unsigned int* __restrict__ flags)
{
    __shared__ __align__(16) char smem[27648];   // As 64x144 | Ws 128x144
    const int tid = threadIdx.x;

    // ---- mask pre-tile blocks (independent of projection) ----
    if (blockIdx.x >= 768) {
        const int mb2 = blockIdx.x - 768;
        const int rb = mb2 >> 5, kt = mb2 & 31;
        float* tile = maskT + ((size_t)rb * 32 + kt) * 8192;   // 2048 slots x 4 fp32
        float4 vals[8];
        bool any = false;
#pragma unroll
        for (int i = 0; i < 8; ++i) {
            int s = tid + i * 256;             // 0..2047
            int l  = s & 63;
            int cb = (s >> 6) & 3;
            int g  = (s >> 8) & 1;
            int w2 = (s >> 9) & 3;
            int qd2 = l >> 4, n2 = l & 15;
            vals[i] = *(const float4*)&mask[
                (size_t)(rb * 128 + w2 * 32 + g * 16 + n2) * SEQ + kt * 64 + cb * 16 + qd2 * 4];
            any = any | (vals[i].x != 0.f) | (vals[i].y != 0.f)
                      | (vals[i].z != 0.f) | (vals[i].w != 0.f);
        }
        unsigned int* nzp = (unsigned int*)smem;
        if (tid == 0) *nzp = 0u;
        __syncthreads();
        if (any) *nzp = 1u;                    // benign race (all write 1)
        __syncthreads();
        if (*nzp) {
#pragma unroll
            for (int i = 0; i < 8; ++i) {
                int s = tid + i * 256;
                *(float4*)&tile[(size_t)s * 4] = vals[i];
            }
            if (tid == 0) atomicOr(&flags[rb], 1u << kt);
        }
        return;
    }

    char* As = smem;
    char* Ws = smem + 9216;

    const int id  = blockIdx.x;
    const int pos = id & 31;
    const int nb  = pos >> 3;
    const int unit = (id >> 5) * 8 + (pos & 7);
    const int mb = unit & 63;
    const int z  = unit >> 6;

    const float* A    = (z == 0) ? q  : (z == 1) ? k  : v;
    const float* W    = (z == 0) ? Wq : (z == 1) ? Wk : Wv;
    const float* bias = (z == 0) ? bq : (z == 1) ? bk : bv;
    unsigned short* Cg = (z == 0) ? Qbf : (z == 1) ? Kbf : Vbf;

    const int w    = tid >> 6;
    const int lane = tid & 63;
    const int qd   = lane >> 4;
    const int n    = lane & 15;
    const int m0 = mb * 64, n0 = nb * 128;

    float4 areg[4], wreg[8];
#pragma unroll
    for (int i = 0; i < 4; ++i) {
        int c = tid + i * 256;                 // A: 1024 chunks, row=c>>4
        areg[i] = *(const float4*)&A[(size_t)(m0 + (c >> 4)) * EMB + (c & 15) * 4];
    }
#pragma unroll
    for (int i = 0; i < 8; ++i) {
        int c = tid + i * 256;                 // W: 2048 chunks, row=c>>4
        wreg[i] = *(const float4*)&W[(size_t)(n0 + (c >> 4)) * EMB + (c & 15) * 4];
    }

    v4f acc[8];
#pragma unroll
    for (int cb = 0; cb < 8; ++cb) acc[cb] = (v4f)0.f;

#pragma unroll 1
    for (int kt = 0; kt < 8; ++kt) {
        __syncthreads();
#pragma unroll
        for (int i = 0; i < 4; ++i) {
            int c = tid + i * 256;
            uint2 pk = { pack2(areg[i].x, areg[i].y), pack2(areg[i].z, areg[i].w) };
            *(uint2*)&As[(c >> 4) * 144 + (c & 15) * 8] = pk;
        }
#pragma unroll
        for (int i = 0; i < 8; ++i) {
            int c = tid + i * 256;
            uint2 pk = { pack2(wreg[i].x, wreg[i].y), pack2(wreg[i].z, wreg[i].w) };
            *(uint2*)&Ws[(c >> 4) * 144 + (c & 15) * 8] = pk;
        }
        __syncthreads();

        if (kt + 1 < 8) {
#pragma unroll
            for (int i = 0; i < 4; ++i) {
                int c = tid + i * 256;
                areg[i] = *(const float4*)&A[(size_t)(m0 + (c >> 4)) * EMB + (kt+1) * 64 + (c & 15) * 4];
            }
#pragma unroll
            for (int i = 0; i < 8; ++i) {
                int c = tid + i * 256;
                wreg[i] = *(const float4*)&W[(size_t)(n0 + (c >> 4)) * EMB + (kt+1) * 64 + (c & 15) * 4];
            }
        }

#pragma unroll
        for (int ks = 0; ks < 2; ++ks) {
            v8s af = *(const v8s*)&As[(w * 16 + n) * 144 + ks * 64 + qd * 16];
#pragma unroll
            for (int cb = 0; cb < 8; ++cb) {
                v8s bfr = *(const v8s*)&Ws[(cb * 16 + n) * 144 + ks * 64 + qd * 16];
                acc[cb] = __builtin_amdgcn_mfma_f32_16x16x32_bf16(af, bfr, acc[cb], 0, 0, 0);
            }
        }
    }

    const float osc = (z == 0) ? 0.02209708691207961f : 1.0f;  // fold scale into Q
    float bb[8];
#pragma unroll
    for (int cb = 0; cb < 8; ++cb) bb[cb] = bias[n0 + cb * 16 + n];
#pragma unroll
    for (int cb = 0; cb < 8; ++cb)
#pragma unroll
        for (int r = 0; r < 4; ++r) acc[cb][r] = (acc[cb][r] + bb[cb]) * osc;

    __syncthreads();
    short* Ct = (short*)smem;                  // Ct[64 rows][136 pitch]
#pragma unroll
    for (int cb = 0; cb < 8; ++cb)
#pragma unroll
        for (int r = 0; r < 4; ++r)
            Ct[(w * 16 + qd * 4 + r) * 136 + cb * 16 + n] = (short)f2bf(acc[cb][r]);
    __syncthreads();
    const int rr = tid >> 2, q4 = tid & 3;
#pragma unroll
    for (int i = 0; i < 4; ++i) {
        uint4 t4 = *(const uint4*)&smem[rr * 272 + q4 * 64 + i * 16];
        *(uint4*)&Cg[(size_t)(m0 + rr) * EMB + n0 + q4 * 32 + i * 8] = t4;
    }
}

// ---------------------------------------------------------------------------
// V tile-transpose (r9-VERIFIED; reads the flat head view): Vbf head block
// [2048][64] -> VtT[bh][kt][d][64] bf16 (contiguous 8 KB tiles). Grid (16,32).
// ---------------------------------------------------------------------------
__global__ __launch_bounds__(256) void vtrans_kernel(
    const unsigned short* __restrict__ Vbf, unsigned short* __restrict__ VtT)
{
    __shared__ unsigned short T[64 * 136];
    const int bh = blockIdx.x, kt = blockIdx.y;
    const int tid = threadIdx.x;
    const unsigned short* Vh = Vbf + (size_t)bh * (SEQ * DH) + (size_t)kt * 64 * DH;
#pragma unroll
    for (int i = 0; i < 2; ++i) {
        int c = tid + i * 256;                 // 512 uint4 chunks, dense
        int s_l = c >> 3, ch = c & 7;
        uint4 t4 = *(const uint4*)&Vh[c * 8];
        const unsigned short* e = (const unsigned short*)&t4;
#pragma unroll
        for (int j = 0; j < 8; ++j)
            T[(ch * 8 + j) * 136 + s_l] = e[j];
    }
    __syncthreads();
    unsigned short* Ot = VtT + ((size_t)bh * 32 + kt) * (64 * 64);
    const int d = tid >> 2, sq = tid & 3;
#pragma unroll
    for (int i = 0; i < 2; ++i) {
        uint4 t4 = *(const uint4*)&T[d * 136 + sq * 16 + i * 8];
        *(uint4*)&Ot[d * 64 + sq * 16 + i * 8] = t4;
    }
}

// ---------------------------------------------------------------------------
// Flash attention, bf16 MFMA, transposed scores, split-K, XCD swizzle (r7).
// Mask tile = C operand of scores MFMA, loaded AT USE POINT (r6/r12 rule) —
// but ONLY if flags[rb] bit kt is set; zero tiles init sacc=0 with no loads.
// Fixed-m softmax (r13). Dense K/V staging (r9). 4 blocks/CU (r14/r17 rule).
// ---------------------------------------------------------------------------
template <int SPLITS>
__global__ __launch_bounds__(256, 4) void attn_kernel(
    const unsigned short* __restrict__ Qbf, const unsigned short* __restrict__ Kbf,
    const unsigned short* __restrict__ VtT,
    const float* __restrict__ maskT, const float* __restrict__ maskf,
    const unsigned int* __restrict__ flags,
    unsigned short* __restrict__ Opart, float* __restrict__ ml,
    float* __restrict__ out)
{
    __shared__ __align__(16) char smem[36864];  // Ks 64x144 | Vts 64x144 | Ps 4x(32x144)
    char* Ks  = smem;
    char* Vts = smem + 9216;

    const int tid  = threadIdx.x;
    const int w    = tid >> 6;
    const int lane = tid & 63;
    const int qd   = lane >> 4;
    const int n    = lane & 15;
    char* Ps = smem + 18432 + w * 4608;

    const int id = blockIdx.x;
    const int rb = ((id >> 3) & 1) * 8 + (id & 7);
    const int bh = (id >> 4) & 15;
    const int kq = id >> 8;
    const int KT0 = kq * (32 / SPLITS), KT1 = KT0 + 32 / SPLITS;

    const unsigned short* Qh = Qbf + (size_t)bh * (SEQ * DH);
    const unsigned short* Kh = Kbf + (size_t)bh * (SEQ * DH);
    const unsigned short* Vth = VtT + (size_t)bh * 32 * 4096;

    const unsigned int fl = (SPLITS > 1) ? flags[rb] : 0u;   // block-uniform

    v8s qf[2][2];
#pragma unroll
    for (int g = 0; g < 2; ++g) {
        const size_t qrow = (size_t)(rb * 128 + w * 32 + g * 16 + n);
#pragma unroll
        for (int ks = 0; ks < 2; ++ks)
            qf[g][ks] = *(const v8s*)&Qh[qrow * DH + ks * 32 + qd * 8];
    }

    // dense staging: thread covers 16B chunks c=tid, c=tid+256 of the 8 KB tile
    uint4 kreg[2], vreg[2];
#pragma unroll
    for (int p = 0; p < 2; ++p) {
        int c = tid + p * 256;
        kreg[p] = *(const uint4*)&Kh[(size_t)KT0 * 4096 + c * 8];
        vreg[p] = *(const uint4*)&Vth[(size_t)KT0 * 4096 + c * 8];
    }

    float l_[2] = { 0.f, 0.f };
    v4f oacc[2][4];
#pragma unroll
    for (int g = 0; g < 2; ++g)
#pragma unroll
        for (int cb = 0; cb < 4; ++cb) oacc[g][cb] = (v4f)0.f;

#pragma unroll 1
    for (int kt = KT0; kt < KT1; ++kt) {
        __syncthreads();
#pragma unroll
        for (int p = 0; p < 2; ++p) {
            int c = tid + p * 256;
            *(uint4*)&Ks [(c >> 3) * 144 + (c & 7) * 16] = kreg[p];
            *(uint4*)&Vts[(c >> 3) * 144 + (c & 7) * 16] = vreg[p];
        }
        __syncthreads();

        // ---- mask tile: only load if nonzero (flag bit); AT USE POINT
        v4f sacc[2][4];
        float4 mk[2][4];
        if (SPLITS > 1) {
            if (fl & (1u << kt)) {
                const float* tileF = maskT + ((size_t)rb * 32 + kt) * 8192;
#pragma unroll
                for (int g = 0; g < 2; ++g)
#pragma unroll
                    for (int cb = 0; cb < 4; ++cb)
                        sacc[g][cb] = *(const v4f*)&tileF[
                            (size_t)((((w * 2 + g) * 4 + cb) * 64) + qd * 16 + n) * 4];
            } else {
#pragma unroll
                for (int g = 0; g < 2; ++g)
#pragma unroll
                    for (int cb = 0; cb < 4; ++cb) sacc[g][cb] = (v4f)0.f;
            }
        } else {
#pragma unroll
            for (int g = 0; g < 2; ++g) {
                const size_t mrow = (size_t)(rb * 128 + w * 32 + g * 16 + n);
#pragma unroll
                for (int cb = 0; cb < 4; ++cb) {
                    mk[g][cb] = *(const float4*)&maskf[mrow * SEQ + kt * 64 + cb * 16 + qd * 4];
                    sacc[g][cb] = (v4f)0.f;
                }
            }
        }

        if (kt + 1 < KT1) {
#pragma unroll
            for (int p = 0; p < 2; ++p) {
                int c = tid + p * 256;
                kreg[p] = *(const uint4*)&Kh[(size_t)(kt + 1) * 4096 + c * 8];
                vreg[p] = *(const uint4*)&Vth[(size_t)(kt + 1) * 4096 + c * 8];
            }
        }

        // ---- scores: S^T[s_k][qrow], accumulated onto the mask tile
#pragma unroll
        for (int ks = 0; ks < 2; ++ks)
#pragma unroll
            for (int cb = 0; cb < 4; ++cb) {
                v8s kf = *(const v8s*)&Ks[(cb * 16 + n) * 144 + ks * 64 + qd * 16];
#pragma unroll
                for (int g = 0; g < 2; ++g)
                    sacc[g][cb] = __builtin_amdgcn_mfma_f32_16x16x32_bf16(kf, qf[g][ks], sacc[g][cb], 0, 0, 0);
            }

        // ---- fixed-m softmax: exp directly, accumulate l, store P
#pragma unroll
        for (int g = 0; g < 2; ++g) {
            float rs = 0.f;
            float pv[4][4];
#pragma unroll
            for (int cb = 0; cb < 4; ++cb) {
                if (SPLITS == 1) {
                    sacc[g][cb][0] += mk[g][cb].x; sacc[g][cb][1] += mk[g][cb].y;
                    sacc[g][cb][2] += mk[g][cb].z; sacc[g][cb][3] += mk[g][cb].w;
                }
#pragma unroll
                for (int r = 0; r < 4; ++r) {
                    float e = __expf(sacc[g][cb][r]);
                    pv[cb][r] = e;
                    rs += e;
                }
            }
            rs += __shfl_xor(rs, 16);
            rs += __shfl_xor(rs, 32);
            l_[g] += rs;
#pragma unroll
            for (int cb = 0; cb < 4; ++cb) {
                uint2 pk = { pack2(pv[cb][0], pv[cb][1]), pack2(pv[cb][2], pv[cb][3]) };
                *(uint2*)&Ps[(g * 16 + n) * 144 + cb * 32 + qd * 8] = pk;
            }
        }

        // ---- PV: O^T[d][qrow] += Vt * P^T
#pragma unroll
        for (int ks = 0; ks < 2; ++ks) {
            v8s pf[2];
#pragma unroll
            for (int g = 0; g < 2; ++g)
                pf[g] = *(const v8s*)&Ps[(g * 16 + n) * 144 + ks * 64 + qd * 16];
#pragma unroll
            for (int cb = 0; cb < 4; ++cb) {
                v8s vf = *(const v8s*)&Vts[(cb * 16 + n) * 144 + ks * 64 + qd * 16];
#pragma unroll
                for (int g = 0; g < 2; ++g)
                    oacc[g][cb] = __builtin_amdgcn_mfma_f32_16x16x32_bf16(vf, pf[g], oacc[g][cb], 0, 0, 0);
            }
        }
    }

    // ---- epilogue
    if (SPLITS == 1) {
#pragma unroll
        for (int g = 0; g < 2; ++g) {
            const float inv = 1.0f / l_[g];
#pragma unroll
            for (int cb = 0; cb < 4; ++cb)
#pragma unroll
                for (int r = 0; r < 4; ++r) oacc[g][cb][r] *= inv;
        }
    } else {
        if (qd == 0) {   // lanes 0..15 hold l for rows g*16+n (dup across qd)
#pragma unroll
            for (int g = 0; g < 2; ++g) {
                const size_t row = (size_t)bh * SEQ + rb * 128 + w * 32 + g * 16 + n;
                ml[(size_t)kq * NROWS + row] = l_[g];
            }
        }
    }
    __syncthreads();
#pragma unroll
    for (int g = 0; g < 2; ++g)
#pragma unroll
        for (int cb = 0; cb < 4; ++cb)
            *(v4f*)&smem[(w * 32 + g * 16 + n) * 272 + cb * 64 + qd * 16] = oacc[g][cb];
    __syncthreads();
    const int r_l = tid >> 1, hf = tid & 1;
    if (SPLITS == 1) {
        float* dst = &out[((size_t)bh * SEQ + rb * 128 + r_l) * DH + hf * 32];
#pragma unroll
        for (int i = 0; i < 8; ++i) {
            float4 t4 = *(const float4*)&smem[r_l * 272 + hf * 128 + i * 16];
            *(float4*)&dst[i * 4] = t4;
        }
    } else {
        unsigned short* dst = &Opart[((size_t)kq * NROWS + (size_t)bh * SEQ + rb * 128 + r_l) * DH + hf * 32];
#pragma unroll
        for (int i = 0; i < 4; ++i) {
            float4 f0 = *(const float4*)&smem[r_l * 272 + hf * 128 + i * 32];
            float4 f1 = *(const float4*)&smem[r_l * 272 + hf * 128 + i * 32 + 16];
            uint4 o = { packh2(f0.x, f0.y), packh2(f0.z, f0.w),
                        packh2(f1.x, f1.y), packh2(f1.z, f1.w) };
            *(uint4*)&dst[i * 8] = o;
        }
    }
}

// ---------------------------------------------------------------------------
// Combine split-K partials (Opart fp16): out = sum_s O_s / sum_s l_s.
// ---------------------------------------------------------------------------
__global__ __launch_bounds__(256) void combine_kernel(
    const unsigned int* __restrict__ Opart, const float* __restrict__ ml,
    float* __restrict__ out, int splits)
{
    const int tid = threadIdx.x;
    const size_t row = (size_t)blockIdx.x * 16 + (tid >> 4);
    const int d4 = (tid & 15) * 4;
    float denom = 0.f;
    float4 o = make_float4(0.f, 0.f, 0.f, 0.f);
    for (int s = 0; s < splits; ++s) {
        denom += ml[(size_t)s * NROWS + row];
        uint2 u = *(const uint2*)&Opart[((size_t)s * NROWS + row) * 32 + (d4 >> 1)];
        v2h h0 = __builtin_bit_cast(v2h, u.x);
        v2h h1 = __builtin_bit_cast(v2h, u.y);
        o.x += (float)h0.x; o.y += (float)h0.y;
        o.z += (float)h1.x; o.w += (float)h1.y;
    }
    const float inv = 1.0f / denom;
    o.x *= inv; o.y *= inv; o.z *= inv; o.w *= inv;
    *(float4*)&out[row * DH + d4] = o;
}

extern "C" void kernel_launch(void* const* d_in, const int* in_sizes, int n_in,
                              void* d_out, int out_size, void* d_ws, size_t ws_size,
                              hipStream_t stream) {
    const float* q    = (const float*)d_in[0];
    const float* k    = (const float*)d_in[1];
    const float* v    = (const float*)d_in[2];
    const float* mask = (const float*)d_in[3];
    const float* Wq   = (const float*)d_in[4];
    const float* bq   = (const float*)d_in[5];
    const float* Wk   = (const float*)d_in[6];
    const float* bk   = (const float*)d_in[7];
    const float* Wv   = (const float*)d_in[8];
    const float* bv   = (const float*)d_in[9];

    char* ws = (char*)d_ws;
    const size_t MB = 1024 * 1024;
    unsigned short* Qbf   = (unsigned short*)(ws + 0);         //  0..4  MB
    unsigned short* Kbf   = (unsigned short*)(ws + 4 * MB);    //  4..8  MB
    unsigned short* VtT   = (unsigned short*)(ws + 8 * MB);    //  8..12 MB
    unsigned short* Opart = (unsigned short*)(ws + 12 * MB);   // 12..28 MB (fp16)
    unsigned short* Vbf   = (unsigned short*)(ws + 12 * MB);   // overlay, dead after vtrans
    float*          mlp   = (float*)(ws + 28 * MB);            // 28..28.5 MB (512 KB used)
    unsigned int*   flags = (unsigned int*)(ws + 28 * MB + 512 * 1024);  // 64 B
    float*          maskT = (float*)(ws + 29 * MB);            // 29..45 MB (fp32)

    const size_t need_split = 45 * MB;                         // ws >= 49 MB proven (r4)
    const bool do_split = ws_size >= need_split;

    if (do_split) {
        (void)hipMemsetAsync(flags, 0, 64, stream);            // zero the 16-word bitmap
        proj_kernel<<<1280, 256, 0, stream>>>(q, k, v, Wq, bq, Wk, bk, Wv, bv,
                                              mask, Qbf, Kbf, Vbf, maskT, flags);
        dim3 tgrid(16, 32);
        vtrans_kernel<<<tgrid, 256, 0, stream>>>(Vbf, VtT);
        attn_kernel<4><<<1024, 256, 0, stream>>>(Qbf, Kbf, VtT, maskT, mask, flags,
                                                 Opart, mlp, (float*)d_out);
        combine_kernel<<<NROWS / 16, 256, 0, stream>>>((const unsigned int*)Opart,
                                                       mlp, (float*)d_out, 4);
    } else {
        proj_kernel<<<768, 256, 0, stream>>>(q, k, v, Wq, bq, Wk, bk, Wv, bv,
                                             mask, Qbf, Kbf, Vbf, maskT, flags);
        dim3 tgrid(16, 32);
        vtrans_kernel<<<tgrid, 256, 0, stream>>>(Vbf, VtT);
        attn_kernel<1><<<256, 256, 0, stream>>>(Qbf, Kbf, VtT, maskT, mask, flags,
                                                Opart, mlp, (float*)d_out);
    }
}